// Round 4
// baseline (174.691 us; speedup 1.0000x reference)
//
#include <hip/hip_runtime.h>
#include <math.h>

// NVFP4 activation quantizer — f32 chain mirroring the reference's XLA
// semantics: the scalar-broadcast division x_abs/scale_per_t is computed as
// x_abs * (1/scale_per_t)  [reciprocal-multiply, XLA's scalar-div rewrite].
// All other ops are single correctly-rounded f32 ops (plain / is CR here —
// verified by rounds 1 vs 3 giving identical results).

__global__ __launch_bounds__(256) void kmax(const float4* __restrict__ x4,
                                            long n4,
                                            unsigned int* __restrict__ gmax) {
    long stride = (long)gridDim.x * blockDim.x;
    float m = 0.0f;
    for (long i = (long)blockIdx.x * blockDim.x + threadIdx.x; i < n4; i += stride) {
        float4 v = x4[i];
        m = fmaxf(m, fmaxf(fmaxf(fabsf(v.x), fabsf(v.y)),
                           fmaxf(fabsf(v.z), fabsf(v.w))));
    }
    #pragma unroll
    for (int off = 32; off > 0; off >>= 1)
        m = fmaxf(m, __shfl_down(m, off, 64));
    __shared__ float sm[4];
    int lane = threadIdx.x & 63;
    int w    = threadIdx.x >> 6;
    if (lane == 0) sm[w] = m;
    __syncthreads();
    if (threadIdx.x == 0) {
        float bm = fmaxf(fmaxf(sm[0], sm[1]), fmaxf(sm[2], sm[3]));
        // non-negative floats: uint compare == float compare (exact max)
        atomicMax(gmax, __float_as_uint(bm));
    }
}

// fp4 (1-2-1) rounding: rintf = RNE = np.round. 2x, x*0.5 exact pow2 scalings.
__device__ __forceinline__ float fp4_121_pos(float x) {
    float s1 = rintf(2.0f * x) * 0.5f;   // x < 2   : spacing 0.5
    float s2 = rintf(x);                 // 2<=x<4  : spacing 1.0
    float s3 = 2.0f * rintf(0.5f * x);   // x >= 4  : spacing 2.0
    return x < 2.0f ? s1 : (x < 4.0f ? s2 : s3);
}

__global__ __launch_bounds__(256) void kquant(const float4* __restrict__ x4,
                                              float4* __restrict__ o4,
                                              const unsigned int* __restrict__ gmax,
                                              long n4) {
    float gm      = __uint_as_float(*gmax);
    float scale_t = gm / 2688.0f;        // CR scalar divide (matches ref)
    float r       = 1.0f / scale_t;      // CR reciprocal — XLA's rewrite
    long stride = (long)gridDim.x * blockDim.x;

    for (long i = (long)blockIdx.x * blockDim.x + threadIdx.x; i < n4; i += stride) {
        float4 v = x4[i];
        // H1: reciprocal-multiply (NOT division) — mirrors ref's
        // x_abs * (1/scale_per_t). Single CR mul each.
        float a0 = fabsf(v.x) * r;
        float a1 = fabsf(v.y) * r;
        float a2 = fabsf(v.z) * r;
        float a3 = fabsf(v.w) * r;

        // block of 16 = 4 adjacent lanes x 4 elems; exact max
        float m = fmaxf(fmaxf(a0, a1), fmaxf(a2, a3));
        m = fmaxf(m, __shfl_xor(m, 1, 64));
        m = fmaxf(m, __shfl_xor(m, 2, 64));

        float inv = 6.0f / m;            // CR division (feeds e4m3 rounding)

        // fp8 e4m3fn roundtrip (ml_dtypes RNE semantics), division-free:
        // quantum q = 2^(max(e,-6)-3); inv*2^(3-e) and *q are EXACT.
        unsigned int u = __float_as_uint(inv);
        int e = (int)(u >> 23) - 127;
        float q, qi;
        if (e < -6) { q = 0x1p-9f; qi = 0x1p+9f; }
        else {
            q  = __uint_as_float((unsigned int)(e + 124) << 23);  // 2^(e-3)
            qi = __uint_as_float((unsigned int)(130 - e) << 23);  // 2^(3-e)
        }
        float sb = rintf(inv * qi) * q;  // exact scalings, RNE tie-break
        if (!(sb > 0.0f && sb <= 448.0f)) sb = 1.0f;

        // quantize: single CR mul feeds the fp4 RNE decision
        float f0 = fp4_121_pos(a0 * sb);
        float f1 = fp4_121_pos(a1 * sb);
        float f2 = fp4_121_pos(a2 * sb);
        float f3 = fp4_121_pos(a3 * sb);

        // ref association: fl(±(f/sb)) * s_t  (post-rounding; CR div)
        float xf0 = f0 / sb;
        float xf1 = f1 / sb;
        float xf2 = f2 / sb;
        float xf3 = f3 / sb;
        float4 o;
        o.x = copysignf(xf0, v.x) * scale_t;
        o.y = copysignf(xf1, v.y) * scale_t;
        o.z = copysignf(xf2, v.z) * scale_t;
        o.w = copysignf(xf3, v.w) * scale_t;
        o4[i] = o;
    }
}

extern "C" void kernel_launch(void* const* d_in, const int* in_sizes, int n_in,
                              void* d_out, int out_size, void* d_ws, size_t ws_size,
                              hipStream_t stream) {
    const float* x = (const float*)d_in[0];
    float* out     = (float*)d_out;
    long n  = (long)in_sizes[0];
    long n4 = n / 4;                      // n = 4*4096*4096, divisible by 16

    unsigned int* gmax = (unsigned int*)d_ws;
    hipMemsetAsync(gmax, 0, sizeof(unsigned int), stream);

    const int threads = 256;
    const int blocks  = 2048;             // grid-stride, ~8 blocks/CU
    kmax<<<blocks, threads, 0, stream>>>((const float4*)x, n4, gmax);
    kquant<<<blocks, threads, 0, stream>>>((const float4*)x, (float4*)out, gmax, n4);
}

// Round 6
// 135.414 us; speedup vs baseline: 1.2901x; 1.2901x over previous
//
#include <hip/hip_runtime.h>
#include <math.h>

// NVFP4 activation quantizer — arithmetic FROZEN from round 4 (absmax 0.0):
//   s_t  = gmax/2688 (CR div);  r = 1/s_t (CR);  a = |x|*r  (XLA rcp-mul)
//   inv  = 6/m (CR div);  sb = e4m3_rne(inv) via exact pow2 scalings
//   out  = copysign(fl(f/sb), x) * s_t   (CR div)
// Memory-movement-only changes vs round 4:
//   - per-block max array (removes memset dispatch + atomic)
//   - nontemporal output store (preserve x in L3 for the second read)
//   - unrolled strided loads for MLP

#define NB 2048   // blocks for both kernels

typedef float vf4 __attribute__((ext_vector_type(4)));  // native vec for nt-store

__global__ __launch_bounds__(256) void kmax(const float4* __restrict__ x4,
                                            long n4,
                                            float* __restrict__ pbmax) {
    long stride = (long)gridDim.x * blockDim.x;
    long i = (long)blockIdx.x * blockDim.x + threadIdx.x;
    float m = 0.0f;
    // unroll 4: four independent coalesced streams
    for (; i + 3 * stride < n4; i += 4 * stride) {
        float4 v0 = x4[i];
        float4 v1 = x4[i + stride];
        float4 v2 = x4[i + 2 * stride];
        float4 v3 = x4[i + 3 * stride];
        float m0 = fmaxf(fmaxf(fabsf(v0.x), fabsf(v0.y)), fmaxf(fabsf(v0.z), fabsf(v0.w)));
        float m1 = fmaxf(fmaxf(fabsf(v1.x), fabsf(v1.y)), fmaxf(fabsf(v1.z), fabsf(v1.w)));
        float m2 = fmaxf(fmaxf(fabsf(v2.x), fabsf(v2.y)), fmaxf(fabsf(v2.z), fabsf(v2.w)));
        float m3 = fmaxf(fmaxf(fabsf(v3.x), fabsf(v3.y)), fmaxf(fabsf(v3.z), fabsf(v3.w)));
        m = fmaxf(m, fmaxf(fmaxf(m0, m1), fmaxf(m2, m3)));
    }
    for (; i < n4; i += stride) {
        float4 v = x4[i];
        m = fmaxf(m, fmaxf(fmaxf(fabsf(v.x), fabsf(v.y)),
                           fmaxf(fabsf(v.z), fabsf(v.w))));
    }
    #pragma unroll
    for (int off = 32; off > 0; off >>= 1)
        m = fmaxf(m, __shfl_down(m, off, 64));
    __shared__ float sm[4];
    int lane = threadIdx.x & 63;
    int w    = threadIdx.x >> 6;
    if (lane == 0) sm[w] = m;
    __syncthreads();
    if (threadIdx.x == 0)
        pbmax[blockIdx.x] = fmaxf(fmaxf(sm[0], sm[1]), fmaxf(sm[2], sm[3]));
}

// fp4 (1-2-1) rounding: rintf = RNE = np.round. Exact pow2 scalings.
__device__ __forceinline__ float fp4_121_pos(float x) {
    float s1 = rintf(2.0f * x) * 0.5f;   // x < 2   : spacing 0.5
    float s2 = rintf(x);                 // 2<=x<4  : spacing 1.0
    float s3 = 2.0f * rintf(0.5f * x);   // x >= 4  : spacing 2.0
    return x < 2.0f ? s1 : (x < 4.0f ? s2 : s3);
}

// One position: load 4 elems, quantize, nt-store. Math identical to round 4.
__device__ __forceinline__ void quant_pos(const float4* __restrict__ x4,
                                          float4* __restrict__ o4,
                                          long i, float scale_t, float r) {
    float4 v = x4[i];
    float a0 = fabsf(v.x) * r;           // rcp-mul (XLA scalar-div rewrite)
    float a1 = fabsf(v.y) * r;
    float a2 = fabsf(v.z) * r;
    float a3 = fabsf(v.w) * r;

    // block of 16 = 4 adjacent lanes x 4 elems; exact max
    float m = fmaxf(fmaxf(a0, a1), fmaxf(a2, a3));
    m = fmaxf(m, __shfl_xor(m, 1, 64));
    m = fmaxf(m, __shfl_xor(m, 2, 64));

    float inv = 6.0f / m;                // CR division

    // fp8 e4m3fn RNE roundtrip, division-free (exact pow2 scalings)
    unsigned int u = __float_as_uint(inv);
    int e = (int)(u >> 23) - 127;
    float q, qi;
    if (e < -6) { q = 0x1p-9f; qi = 0x1p+9f; }
    else {
        q  = __uint_as_float((unsigned int)(e + 124) << 23);  // 2^(e-3)
        qi = __uint_as_float((unsigned int)(130 - e) << 23);  // 2^(3-e)
    }
    float sb = rintf(inv * qi) * q;
    if (!(sb > 0.0f && sb <= 448.0f)) sb = 1.0f;

    float f0 = fp4_121_pos(a0 * sb);
    float f1 = fp4_121_pos(a1 * sb);
    float f2 = fp4_121_pos(a2 * sb);
    float f3 = fp4_121_pos(a3 * sb);

    float xf0 = f0 / sb;                 // CR division (ref association)
    float xf1 = f1 / sb;
    float xf2 = f2 / sb;
    float xf3 = f3 / sb;
    vf4 o;
    o.x = copysignf(xf0, v.x) * scale_t;
    o.y = copysignf(xf1, v.y) * scale_t;
    o.z = copysignf(xf2, v.z) * scale_t;
    o.w = copysignf(xf3, v.w) * scale_t;
    __builtin_nontemporal_store(o, (vf4*)&o4[i]);   // don't evict x from L3
}

__global__ __launch_bounds__(256) void kquant(const float4* __restrict__ x4,
                                              float4* __restrict__ o4,
                                              const float* __restrict__ pbmax,
                                              long n4) {
    // reduce per-block maxima (exact, order-independent)
    float lm = 0.0f;
    for (int j = threadIdx.x; j < NB; j += 256)
        lm = fmaxf(lm, pbmax[j]);
    #pragma unroll
    for (int off = 32; off > 0; off >>= 1)
        lm = fmaxf(lm, __shfl_down(lm, off, 64));
    __shared__ float sm[4];
    int lane = threadIdx.x & 63;
    int w    = threadIdx.x >> 6;
    if (lane == 0) sm[w] = lm;
    __syncthreads();
    float gm = fmaxf(fmaxf(sm[0], sm[1]), fmaxf(sm[2], sm[3]));

    float scale_t = gm / 2688.0f;        // CR scalar divide (= ref)
    float r       = 1.0f / scale_t;      // CR reciprocal (XLA rewrite)

    long stride = (long)gridDim.x * blockDim.x;
    long i = (long)blockIdx.x * blockDim.x + threadIdx.x;
    // n4 % 64 == 0 and stride % 64 == 0 -> loop bounds are wave-uniform,
    // so the shfl_xor block-max never sees inactive partner lanes.
    for (; i + stride < n4; i += 2 * stride) {
        quant_pos(x4, o4, i,          scale_t, r);
        quant_pos(x4, o4, i + stride, scale_t, r);
    }
    for (; i < n4; i += stride)
        quant_pos(x4, o4, i, scale_t, r);
}

extern "C" void kernel_launch(void* const* d_in, const int* in_sizes, int n_in,
                              void* d_out, int out_size, void* d_ws, size_t ws_size,
                              hipStream_t stream) {
    const float* x = (const float*)d_in[0];
    float* out     = (float*)d_out;
    long n  = (long)in_sizes[0];
    long n4 = n / 4;                      // 4*4096*4096 / 4 = 2^24

    float* pbmax = (float*)d_ws;          // NB floats, fully rewritten each call

    kmax<<<NB, 256, 0, stream>>>((const float4*)x, n4, pbmax);
    kquant<<<NB, 256, 0, stream>>>((const float4*)x, (float4*)out, pbmax, n4);
}